// Round 5
// baseline (1177.004 us; speedup 1.0000x reference)
//
#include <hip/hip_runtime.h>
#include <stdint.h>

typedef __bf16 bf16_t;
typedef __bf16 bf16x8 __attribute__((ext_vector_type(8)));
typedef float  f32x4  __attribute__((ext_vector_type(4)));
typedef unsigned short u16x4 __attribute__((ext_vector_type(4)));

__device__ __forceinline__ void gl_lds16(const void* g, void* lds) {
  __builtin_amdgcn_global_load_lds(
      (const __attribute__((address_space(1))) uint32_t*)g,
      (__attribute__((address_space(3))) uint32_t*)lds, 16, 0, 0);
}

// C[m][n] = (sum_k A[m][k] * BT[n][k]) * scale + bias[n] (+ res[m][n])
// A: M x K bf16 (lda), BT: N x K bf16 (ldb). 128x128 tile, BK=32,
// 256 thr = 4 waves (2x2), each wave 64x64 = 4x4 of mfma_f32_16x16x32_bf16.
template<bool OUT_BF16, bool HAS_BIAS, bool HAS_RES>
__global__ __launch_bounds__(256)
void gemm_bt(const bf16_t* __restrict__ A, int64_t lda, int64_t sA,
             const bf16_t* __restrict__ BT, int64_t ldb, int64_t sB,
             void* __restrict__ Cv, int64_t ldc, int64_t sC,
             const float* __restrict__ bias, const float* __restrict__ res,
             float scale, int K)
{
  __shared__ __align__(16) bf16_t lA[128 * 32];
  __shared__ __align__(16) bf16_t lB[128 * 32];
  const int t = threadIdx.x;
  const int z = blockIdx.z;

  // T1: XCD swizzle (bijective only when nwg % 8 == 0 — true for all launches here)
  const int gx  = gridDim.x;
  const int nwg = gx * gridDim.y;
  int flat = blockIdx.y * gx + blockIdx.x;
  if ((nwg & 7) == 0) flat = (flat & 7) * (nwg >> 3) + (flat >> 3);
  const int tn = flat % gx;
  const int tm = flat / gx;

  const bf16_t* Ab = A + (int64_t)z * sA;
  const bf16_t* Bb = BT + (int64_t)z * sB;
  const int64_t bm = (int64_t)tm * 128;
  const int64_t bn = (int64_t)tn * 128;
  const int l   = t & 63;
  const int wid = t >> 6;
  const int wm  = (wid >> 1) * 64;
  const int wn  = (wid & 1) * 64;
  const int lr  = l & 15;
  const int kg  = l >> 4;
  const int srow = t >> 2;
  const int scol = (t & 3) * 8;
  char* lAc = (char*)lA;
  char* lBc = (char*)lB;
  const int wbase = (t & 192) * 16;

  f32x4 acc[4][4] = {};

  for (int k0 = 0; k0 < K; k0 += 32) {
    const bf16_t* ga = Ab + (bm + srow) * lda + k0 + scol;
    const bf16_t* gb = Bb + (bn + srow) * ldb + k0 + scol;
    gl_lds16(ga,            lAc + wbase);
    gl_lds16(ga + 64 * lda, lAc + 4096 + wbase);
    gl_lds16(gb,            lBc + wbase);
    gl_lds16(gb + 64 * ldb, lBc + 4096 + wbase);
    __syncthreads();
    bf16x8 af[4], bfv[4];
#pragma unroll
    for (int m = 0; m < 4; ++m)
      af[m] = *(const bf16x8*)(lA + (wm + m * 16 + lr) * 32 + kg * 8);
#pragma unroll
    for (int n = 0; n < 4; ++n)
      bfv[n] = *(const bf16x8*)(lB + (wn + n * 16 + lr) * 32 + kg * 8);
#pragma unroll
    for (int m = 0; m < 4; ++m)
#pragma unroll
      for (int n = 0; n < 4; ++n)
        acc[m][n] = __builtin_amdgcn_mfma_f32_16x16x32_bf16(af[m], bfv[n], acc[m][n], 0, 0, 0);
    __syncthreads();
  }

  bf16_t* C16 = (bf16_t*)Cv + (int64_t)z * sC;
  float*  C32 = (float*)Cv + (int64_t)z * sC;
#pragma unroll
  for (int m = 0; m < 4; ++m) {
#pragma unroll
    for (int n = 0; n < 4; ++n) {
      const int64_t col = bn + wn + n * 16 + lr;
      const float bv = HAS_BIAS ? bias[col] : 0.0f;
#pragma unroll
      for (int r = 0; r < 4; ++r) {
        const int64_t row = bm + wm + m * 16 + kg * 4 + r;
        float v = acc[m][n][r] * scale + bv;
        if constexpr (HAS_RES) v += res[row * ldc + col];
        if constexpr (OUT_BF16) C16[row * ldc + col] = (bf16_t)v;
        else                    C32[row * ldc + col] = v;
      }
    }
  }
}

// Fused flash attention for one encoder layer.
// Grid (32 qtiles, 16 heads), 256 thr = 4 waves; each wave owns 16 q-rows.
// K/V read straight from global (L2-resident: 1 MB/head); Q in registers;
// LDS only for the wave-private P round-trip (C-layout -> A-layout), with
// XOR-16B swizzle on both sides. Zero barriers.
// Writes O transposed into CTXT rows (head*128+d), cols s.
__global__ __launch_bounds__(256)
void flash_attn(const bf16_t* __restrict__ QKV,   // S x 6144
                const bf16_t* __restrict__ VT,    // 2048 x 2048 feature-major
                bf16_t* __restrict__ CTXT)        // 2048 x 2048
{
  __shared__ __align__(16) bf16_t Plds[64 * 128];
  const int t = threadIdx.x;
  const int w = t >> 6, l = t & 63, lo = l & 15, hi = l >> 4;
  const int head = blockIdx.y;
  const int qt = blockIdx.x;
  const int q0 = qt * 64 + w * 16;

  // Q A-frags: row = lo, k = 32*kk + hi*8 + j
  const bf16_t* qp = QKV + (int64_t)(q0 + lo) * 6144 + head * 128 + hi * 8;
  bf16x8 qf[4];
#pragma unroll
  for (int kk = 0; kk < 4; ++kk) qf[kk] = *(const bf16x8*)(qp + 32 * kk);

  const bf16_t* kbase = QKV + 2048 + head * 128;
  const bf16_t* vbase = VT + (int64_t)(head * 128) * 2048;

  float m_r[4], l_r[4];
  f32x4 Oacc[8] = {};
#pragma unroll
  for (int r = 0; r < 4; ++r) { m_r[r] = -3.0e38f; l_r[r] = 0.f; }

  const float c1 = 0.08838834764831845f * 1.4426950408889634f; // 1/sqrt(dk)*log2e

  char* pw = (char*)(Plds + w * 16 * 128);  // wave-private 16x128 region

  for (int tile = 0; tile < 16; ++tile) {
    const int kv0 = tile * 128;
    f32x4 Sacc[8] = {};
    // ---- scores: S[qrow][kv] = Q . K^T
#pragma unroll
    for (int kk = 0; kk < 4; ++kk) {
      bf16x8 kb[8];
#pragma unroll
      for (int n = 0; n < 8; ++n)
        kb[n] = *(const bf16x8*)(kbase + (int64_t)(kv0 + n * 16 + lo) * 6144 + kk * 32 + hi * 8);
#pragma unroll
      for (int n = 0; n < 8; ++n)
        Sacc[n] = __builtin_amdgcn_mfma_f32_16x16x32_bf16(qf[kk], kb[n], Sacc[n], 0, 0, 0);
    }
    // ---- online softmax (t-units: raw*c1), rows = hi*4+r, reduce across l&15
    float corr[4];
#pragma unroll
    for (int r = 0; r < 4; ++r) {
      float mx = Sacc[0][r];
#pragma unroll
      for (int n = 1; n < 8; ++n) mx = fmaxf(mx, Sacc[n][r]);
#pragma unroll
      for (int off = 1; off < 16; off <<= 1) mx = fmaxf(mx, __shfl_xor(mx, off));
      const float mt = mx * c1;
      const float mnew = fmaxf(m_r[r], mt);
      corr[r] = exp2f(m_r[r] - mnew);
      m_r[r] = mnew;
    }
    float psum[4] = {0.f, 0.f, 0.f, 0.f};
#pragma unroll
    for (int n = 0; n < 8; ++n) {
#pragma unroll
      for (int r = 0; r < 4; ++r) {
        const float p = exp2f(Sacc[n][r] * c1 - m_r[r]);
        psum[r] += p;
        const int row = hi * 4 + r;                       // wave-local row
        const int byte = row * 256 + (n * 16 + lo) * 2;
        *(bf16_t*)(pw + (byte ^ ((row & 7) << 4))) = (bf16_t)p;
      }
    }
#pragma unroll
    for (int r = 0; r < 4; ++r) {
#pragma unroll
      for (int off = 1; off < 16; off <<= 1) psum[r] += __shfl_xor(psum[r], off);
      l_r[r] = l_r[r] * corr[r] + psum[r];
    }
#pragma unroll
    for (int n = 0; n < 8; ++n) {
      Oacc[n][0] *= corr[0]; Oacc[n][1] *= corr[1];
      Oacc[n][2] *= corr[2]; Oacc[n][3] *= corr[3];
    }
    asm volatile("s_waitcnt lgkmcnt(0)" ::: "memory");
    __builtin_amdgcn_sched_barrier(0);
    // ---- PV: O[qrow][d] += P . V ; A = P from LDS (row=lo), B = VT rows
#pragma unroll
    for (int kk = 0; kk < 4; ++kk) {
      const int byteA = lo * 256 + (((kk * 4 + hi) ^ (lo & 7)) << 4);
      const bf16x8 pa = *(const bf16x8*)(pw + byteA);
#pragma unroll
      for (int n = 0; n < 8; ++n) {
        const bf16x8 vb = *(const bf16x8*)(vbase + (int64_t)(n * 16 + lo) * 2048 + kv0 + kk * 32 + hi * 8);
        Oacc[n] = __builtin_amdgcn_mfma_f32_16x16x32_bf16(pa, vb, Oacc[n], 0, 0, 0);
      }
    }
    __builtin_amdgcn_sched_barrier(0);
  }
  // ---- epilogue: normalize, write O^T into CTXT
  float inv[4];
#pragma unroll
  for (int r = 0; r < 4; ++r) inv[r] = 1.0f / l_r[r];
#pragma unroll
  for (int n = 0; n < 8; ++n) {
    u16x4 o;
#pragma unroll
    for (int r = 0; r < 4; ++r) {
      const bf16_t b = (bf16_t)(Oacc[n][r] * inv[r]);
      o[r] = *(const unsigned short*)&b;
    }
    *(u16x4*)(CTXT + (int64_t)(head * 128 + n * 16 + lo) * 2048 + qt * 64 + w * 16 + hi * 4) = o;
  }
}

// out[c][r] = bf16(in[r][c]); grid (cols/32, rows/32), block 256 flat.
template<typename TIN>
__device__ __forceinline__
void transpose_body(const TIN* __restrict__ in, int64_t ldi,
                    bf16_t* __restrict__ out, int64_t ldo)
{
  __shared__ float tile[32][33];
  const int bx = blockIdx.x * 32;
  const int by = blockIdx.y * 32;
  const int tx = threadIdx.x & 31;
  const int ty = threadIdx.x >> 5;
#pragma unroll
  for (int i = 0; i < 32; i += 8)
    tile[ty + i][tx] = (float)in[(int64_t)(by + ty + i) * ldi + bx + tx];
  __syncthreads();
#pragma unroll
  for (int i = 0; i < 32; i += 8)
    out[(int64_t)(bx + ty + i) * ldo + by + tx] = (bf16_t)tile[tx][ty + i];
}

template<typename TIN>
__global__ __launch_bounds__(256)
void transpose_to_bf16(const TIN* __restrict__ in, int64_t ldi,
                       bf16_t* __restrict__ out, int64_t ldo)
{
  transpose_body<TIN>(in, ldi, out, ldo);
}

struct Ptr10 { const float* p[10]; };

__global__ __launch_bounds__(256)
void weight_prep(Ptr10 ws, bf16_t* __restrict__ out, int64_t stride)
{
  transpose_body<float>(ws.p[blockIdx.z], 2048, out + (int64_t)blockIdx.z * stride, 2048);
}

__global__ __launch_bounds__(256)
void f32_to_bf16_k(const float* __restrict__ in, bf16_t* __restrict__ out)
{
  const int64_t i = ((int64_t)blockIdx.x * 256 + threadIdx.x) * 8;
  const float4 a = *(const float4*)(in + i);
  const float4 b = *(const float4*)(in + i + 4);
  bf16x8 o;
  o[0] = (bf16_t)a.x; o[1] = (bf16_t)a.y; o[2] = (bf16_t)a.z; o[3] = (bf16_t)a.w;
  o[4] = (bf16_t)b.x; o[5] = (bf16_t)b.y; o[6] = (bf16_t)b.z; o[7] = (bf16_t)b.w;
  *(bf16x8*)(out + i) = o;
}

// LN(y)*g + b -> xout (fp32) and xb (bf16). One block per row.
__global__ __launch_bounds__(256)
void add_ln(const float* __restrict__ y,
            const float* __restrict__ g, const float* __restrict__ b,
            float* __restrict__ xout, bf16_t* __restrict__ xb)
{
  const int64_t row = blockIdx.x;
  const int t = threadIdx.x;
  const int64_t base = row * 2048 + t * 8;
  const float4 y0 = *(const float4*)(y + base);
  const float4 y1 = *(const float4*)(y + base + 4);
  float x[8] = {y0.x, y0.y, y0.z, y0.w, y1.x, y1.y, y1.z, y1.w};
  float s = 0.f, q = 0.f;
#pragma unroll
  for (int j = 0; j < 8; ++j) { s += x[j]; q += x[j] * x[j]; }
#pragma unroll
  for (int off = 32; off; off >>= 1) { s += __shfl_xor(s, off); q += __shfl_xor(q, off); }
  __shared__ float rs[4], rq[4];
  const int l = t & 63, w = t >> 6;
  if (l == 0) { rs[w] = s; rq[w] = q; }
  __syncthreads();
  s = rs[0] + rs[1] + rs[2] + rs[3];
  q = rq[0] + rq[1] + rq[2] + rq[3];
  const float mean = s * (1.f / 2048.f);
  const float var  = q * (1.f / 2048.f) - mean * mean;
  const float inv  = rsqrtf(var + 1e-5f);
  const float4 g0 = *(const float4*)(g + t * 8);
  const float4 g1 = *(const float4*)(g + t * 8 + 4);
  const float4 b0 = *(const float4*)(b + t * 8);
  const float4 b1 = *(const float4*)(b + t * 8 + 4);
  float o[8];
  o[0] = (x[0] - mean) * inv * g0.x + b0.x; o[1] = (x[1] - mean) * inv * g0.y + b0.y;
  o[2] = (x[2] - mean) * inv * g0.z + b0.z; o[3] = (x[3] - mean) * inv * g0.w + b0.w;
  o[4] = (x[4] - mean) * inv * g1.x + b1.x; o[5] = (x[5] - mean) * inv * g1.y + b1.y;
  o[6] = (x[6] - mean) * inv * g1.z + b1.z; o[7] = (x[7] - mean) * inv * g1.w + b1.w;
  *(float4*)(xout + base)     = make_float4(o[0], o[1], o[2], o[3]);
  *(float4*)(xout + base + 4) = make_float4(o[4], o[5], o[6], o[7]);
  bf16x8 ob;
#pragma unroll
  for (int j = 0; j < 8; ++j) ob[j] = (bf16_t)o[j];
  *(bf16x8*)(xb + base) = ob;
}

extern "C" void kernel_launch(void* const* d_in, const int* in_sizes, int n_in,
                              void* d_out, int out_size, void* d_ws, size_t ws_size,
                              hipStream_t stream)
{
  constexpr int S = 2048, D = 2048;
  constexpr int64_t DD = (int64_t)D * D;

  const float* X    = (const float*)d_in[0];
  const float* wq1  = (const float*)d_in[1];
  const float* wk1  = (const float*)d_in[2];
  const float* wv1  = (const float*)d_in[3];
  const float* wfc1 = (const float*)d_in[4];
  const float* bfc1 = (const float*)d_in[5];
  const float* g1   = (const float*)d_in[6];
  const float* b1   = (const float*)d_in[7];
  const float* wl1  = (const float*)d_in[8];
  const float* bl1  = (const float*)d_in[9];
  const float* g2   = (const float*)d_in[10];
  const float* b2   = (const float*)d_in[11];
  const float* wq2  = (const float*)d_in[12];
  const float* wk2  = (const float*)d_in[13];
  const float* wv2  = (const float*)d_in[14];
  const float* wfc2 = (const float*)d_in[15];
  const float* bfc2 = (const float*)d_in[16];
  const float* g3   = (const float*)d_in[17];
  const float* b3   = (const float*)d_in[18];
  const float* wl2  = (const float*)d_in[19];
  const float* bl2  = (const float*)d_in[20];
  const float* g4   = (const float*)d_in[21];
  const float* b4   = (const float*)d_in[22];

  // workspace layout
  char* p = (char*)d_ws;
  bf16_t* WT  = (bf16_t*)p; p += 10 * DD * 2;            // transposed bf16 weights
  bf16_t* Xb  = (bf16_t*)p; p += DD * 2;                 // current X bf16
  bf16_t* QKV = (bf16_t*)p; p += (int64_t)S * 3 * D * 2; // S x 6144
  bf16_t* VT  = (bf16_t*)p; p += DD * 2;                 // V^T feature-major
  bf16_t* CTXT= (bf16_t*)p; p += DD * 2;                 // ctx^T (= scrambled reshape)
  float*  OUTF= (float*)p;  p += DD * 4;                 // fp32 GEMM out (+res)
  float*  XF  = (float*)p;                               // current X fp32

  const dim3 TB(256);

  auto gemm = [&](const bf16_t* A, int64_t lda,
                  const bf16_t* BT, int64_t ldb,
                  void* C, int64_t ldc,
                  const float* bias, const float* res, float scale,
                  int M, int N, int K, bool obf) {
    dim3 gg(N / 128, M / 128, 1);
    if (obf) gemm_bt<true, false, false><<<gg, TB, 0, stream>>>(A, lda, 0, BT, ldb, 0, C, ldc, 0, nullptr, nullptr, scale, K);
    else     gemm_bt<false, true, true ><<<gg, TB, 0, stream>>>(A, lda, 0, BT, ldb, 0, C, ldc, 0, bias, res, scale, K);
  };

  Ptr10 wsrc = {{wq1, wk1, wv1, wfc1, wl1, wq2, wk2, wv2, wfc2, wl2}};
  weight_prep<<<dim3(64, 64, 10), TB, 0, stream>>>(wsrc, WT, DD);
  f32_to_bf16_k<<<dim3(DD / 2048), TB, 0, stream>>>(X, Xb);

  auto layer = [&](const float* resX, int sq, int sfc, int sfl,
                   const float* bfc, const float* ga, const float* ba,
                   const float* bl, const float* gb, const float* bb,
                   float* ln2_out) {
    // fused QKV projection (weight slots sq..sq+2 contiguous)
    gemm(Xb, D, WT + (int64_t)sq * DD, D, QKV, 3 * D, nullptr, nullptr, 1.f, S, 3 * D, D, true);
    // V^T (feature-major; per-head V_h^T stacked)
    transpose_to_bf16<bf16_t><<<dim3(64, 64), TB, 0, stream>>>(QKV + 2 * D, 3 * D, VT, S);
    // fused attention -> CTXT
    flash_attn<<<dim3(32, 16), TB, 0, stream>>>(QKV, VT, CTXT);
    // fc on scrambled-reshape matrix (= CTXT), residual fused
    gemm(CTXT, S, WT + (int64_t)sfc * DD, D, OUTF, D, bfc, resX, 1.f, D, D, S, false);
    add_ln<<<dim3(S), TB, 0, stream>>>(OUTF, ga, ba, XF, Xb);
    // FFN linear, residual fused
    gemm(Xb, D, WT + (int64_t)sfl * DD, D, OUTF, D, bl, XF, 1.f, S, D, D, false);
    add_ln<<<dim3(S), TB, 0, stream>>>(OUTF, gb, bb, ln2_out, Xb);
  };

  layer(X,  0, 3, 4, bfc1, g1, b1, bl1, g2, b2, XF);
  layer(XF, 5, 8, 9, bfc2, g3, b3, bl2, g4, b4, (float*)d_out);
}

// Round 6
// 849.385 us; speedup vs baseline: 1.3857x; 1.3857x over previous
//
#include <hip/hip_runtime.h>
#include <stdint.h>

typedef __bf16 bf16_t;
typedef __bf16 bf16x8 __attribute__((ext_vector_type(8)));
typedef float  f32x4  __attribute__((ext_vector_type(4)));
typedef unsigned short u16x4 __attribute__((ext_vector_type(4)));

__device__ __forceinline__ void gl_lds16(const void* g, void* lds) {
  __builtin_amdgcn_global_load_lds(
      (const __attribute__((address_space(1))) uint32_t*)g,
      (__attribute__((address_space(3))) uint32_t*)lds, 16, 0, 0);
}

// C[m][n] = (sum_k A[m][k] * BT[n][k]) * scale + bias[n] (+ res[m][n])
// A: M x K bf16 (lda), BT: N x K bf16 (ldb). 128x128 tile, BK=32,
// 256 thr = 4 waves (2x2), each wave 64x64 = 4x4 of mfma_f32_16x16x32_bf16.
template<bool OUT_BF16, bool HAS_BIAS, bool HAS_RES>
__global__ __launch_bounds__(256)
void gemm_bt(const bf16_t* __restrict__ A, int64_t lda, int64_t sA,
             const bf16_t* __restrict__ BT, int64_t ldb, int64_t sB,
             void* __restrict__ Cv, int64_t ldc, int64_t sC,
             const float* __restrict__ bias, const float* __restrict__ res,
             float scale, int K)
{
  __shared__ __align__(16) bf16_t lA[128 * 32];
  __shared__ __align__(16) bf16_t lB[128 * 32];
  const int t = threadIdx.x;
  const int z = blockIdx.z;

  // T1: XCD swizzle (bijective only when nwg % 8 == 0 — true for all launches here)
  const int gx  = gridDim.x;
  const int nwg = gx * gridDim.y;
  int flat = blockIdx.y * gx + blockIdx.x;
  if ((nwg & 7) == 0) flat = (flat & 7) * (nwg >> 3) + (flat >> 3);
  const int tn = flat % gx;
  const int tm = flat / gx;

  const bf16_t* Ab = A + (int64_t)z * sA;
  const bf16_t* Bb = BT + (int64_t)z * sB;
  const int64_t bm = (int64_t)tm * 128;
  const int64_t bn = (int64_t)tn * 128;
  const int l   = t & 63;
  const int wid = t >> 6;
  const int wm  = (wid >> 1) * 64;
  const int wn  = (wid & 1) * 64;
  const int lr  = l & 15;
  const int kg  = l >> 4;
  const int srow = t >> 2;
  const int scol = (t & 3) * 8;
  char* lAc = (char*)lA;
  char* lBc = (char*)lB;
  const int wbase = (t & 192) * 16;

  f32x4 acc[4][4] = {};

  for (int k0 = 0; k0 < K; k0 += 32) {
    const bf16_t* ga = Ab + (bm + srow) * lda + k0 + scol;
    const bf16_t* gb = Bb + (bn + srow) * ldb + k0 + scol;
    gl_lds16(ga,            lAc + wbase);
    gl_lds16(ga + 64 * lda, lAc + 4096 + wbase);
    gl_lds16(gb,            lBc + wbase);
    gl_lds16(gb + 64 * ldb, lBc + 4096 + wbase);
    __syncthreads();
    bf16x8 af[4], bfv[4];
#pragma unroll
    for (int m = 0; m < 4; ++m)
      af[m] = *(const bf16x8*)(lA + (wm + m * 16 + lr) * 32 + kg * 8);
#pragma unroll
    for (int n = 0; n < 4; ++n)
      bfv[n] = *(const bf16x8*)(lB + (wn + n * 16 + lr) * 32 + kg * 8);
#pragma unroll
    for (int m = 0; m < 4; ++m)
#pragma unroll
      for (int n = 0; n < 4; ++n)
        acc[m][n] = __builtin_amdgcn_mfma_f32_16x16x32_bf16(af[m], bfv[n], acc[m][n], 0, 0, 0);
    __syncthreads();
  }

  bf16_t* C16 = (bf16_t*)Cv + (int64_t)z * sC;
  float*  C32 = (float*)Cv + (int64_t)z * sC;
#pragma unroll
  for (int m = 0; m < 4; ++m) {
#pragma unroll
    for (int n = 0; n < 4; ++n) {
      const int64_t col = bn + wn + n * 16 + lr;
      const float bv = HAS_BIAS ? bias[col] : 0.0f;
#pragma unroll
      for (int r = 0; r < 4; ++r) {
        const int64_t row = bm + wm + m * 16 + kg * 4 + r;
        float v = acc[m][n][r] * scale + bv;
        if constexpr (HAS_RES) v += res[row * ldc + col];
        if constexpr (OUT_BF16) C16[row * ldc + col] = (bf16_t)v;
        else                    C32[row * ldc + col] = v;
      }
    }
  }
}

// Fused flash attention, LDS-staged K/V (gemm_bt 2-barrier pattern).
// Grid (32 qtiles, 16 heads), 256 thr = 4 waves; each wave owns 16 q-rows.
// Per kv-tile (KVBLK=64): stage K[64][128] and V^T[128][64] into LDS via
// global_load_lds (linear dest, inverse-XOR-swizzled SOURCE; reads use the
// same XOR — rule 21). P round-trip stays wave-private (no barrier).
// Writes O transposed into CTXT rows (head*128+d), cols q.
__global__ __launch_bounds__(256)
void flash_attn(const bf16_t* __restrict__ QKV,   // S x 6144
                const bf16_t* __restrict__ VT,    // 2048 x 2048 feature-major
                bf16_t* __restrict__ CTXT)        // 2048 x 2048
{
  __shared__ __align__(16) bf16_t lK[64 * 128];   // [kv][dk]   row 256 B, swizzled
  __shared__ __align__(16) bf16_t lV[128 * 64];   // [dk][kv]   row 128 B, swizzled
  __shared__ __align__(16) bf16_t lP[4][16 * 64]; // per-wave P, row 128 B, swizzled
  const int t = threadIdx.x;
  const int w = t >> 6, l = t & 63, lo = l & 15, hi = l >> 4;
  const int head = blockIdx.y;
  const int qt = blockIdx.x;
  const int q0 = qt * 64 + w * 16;
  const int wbase = (t & 192) * 16;  // wave-uniform LDS byte base (w*1024)

  // Q A-frags: row = lo, k = 32*kk + hi*8 + j
  const bf16_t* qp = QKV + (int64_t)(q0 + lo) * 6144 + head * 128 + hi * 8;
  bf16x8 qf[4];
#pragma unroll
  for (int kk = 0; kk < 4; ++kk) qf[kk] = *(const bf16x8*)(qp + 32 * kk);

  const bf16_t* kbase = QKV + 2048 + head * 128;           // [kv][*] ld 6144
  const bf16_t* vbase = VT + (int64_t)(head * 128) * 2048; // [dk][kv] ld 2048

  float m_r[4], l_r[4];
  f32x4 Oacc[8] = {};
#pragma unroll
  for (int r = 0; r < 4; ++r) { m_r[r] = -3.0e38f; l_r[r] = 0.f; }

  const float c1 = 0.08838834764831845f * 1.4426950408889634f; // 1/sqrt(dk)*log2e

  char* lKc = (char*)lK;
  char* lVc = (char*)lV;
  char* pw  = (char*)lP[w];

  for (int tile = 0; tile < 32; ++tile) {
    const int kv0 = tile * 64;
    // ---- stage K tile: 16 KB, 4 rounds; dest linear, source inverse-swizzled
#pragma unroll
    for (int c = 0; c < 4; ++c) {
      const int row = c * 16 + (t >> 4);                 // kv-local 0..63
      const int srcb = ((t & 15) * 16) ^ ((row & 7) << 4);
      gl_lds16(kbase + (int64_t)(kv0 + row) * 6144 + (srcb >> 1), lKc + c * 4096 + wbase);
    }
    // ---- stage V^T tile: 16 KB, 4 rounds
#pragma unroll
    for (int c = 0; c < 4; ++c) {
      const int row = c * 32 + (t >> 3);                 // dk-local 0..127
      const int srcb = ((t & 7) * 16) ^ ((row & 7) << 4);
      gl_lds16(vbase + (int64_t)row * 2048 + kv0 + (srcb >> 1), lVc + c * 4096 + wbase);
    }
    __syncthreads();

    // ---- scores: S[q][kv] = Q . K^T  (B-frags from swizzled lK)
    f32x4 Sacc[4] = {};
#pragma unroll
    for (int kk = 0; kk < 4; ++kk) {
      bf16x8 kb[4];
#pragma unroll
      for (int n = 0; n < 4; ++n) {
        const int row = n * 16 + lo;
        kb[n] = *(const bf16x8*)(lKc + row * 256 + ((kk * 64 + hi * 16) ^ ((row & 7) << 4)));
      }
#pragma unroll
      for (int n = 0; n < 4; ++n)
        Sacc[n] = __builtin_amdgcn_mfma_f32_16x16x32_bf16(qf[kk], kb[n], Sacc[n], 0, 0, 0);
    }

    // ---- online softmax; q-row = hi*4+r, kv = n*16+lo; reduce across lo lanes
    float corr[4];
#pragma unroll
    for (int r = 0; r < 4; ++r) {
      float mx = Sacc[0][r];
#pragma unroll
      for (int n = 1; n < 4; ++n) mx = fmaxf(mx, Sacc[n][r]);
#pragma unroll
      for (int off = 1; off < 16; off <<= 1) mx = fmaxf(mx, __shfl_xor(mx, off));
      const float mt = mx * c1;
      const float mnew = fmaxf(m_r[r], mt);
      corr[r] = exp2f(m_r[r] - mnew);
      m_r[r] = mnew;
    }
    float psum[4] = {0.f, 0.f, 0.f, 0.f};
#pragma unroll
    for (int n = 0; n < 4; ++n) {
#pragma unroll
      for (int r = 0; r < 4; ++r) {
        const float p = exp2f(Sacc[n][r] * c1 - m_r[r]);
        psum[r] += p;
        const int row = hi * 4 + r;
        const int byte = row * 128 + (((n * 16 + lo) * 2) ^ ((row & 7) << 4));
        *(bf16_t*)(pw + byte) = (bf16_t)p;
      }
    }
#pragma unroll
    for (int r = 0; r < 4; ++r) {
#pragma unroll
      for (int off = 1; off < 16; off <<= 1) psum[r] += __shfl_xor(psum[r], off);
      l_r[r] = l_r[r] * corr[r] + psum[r];
    }
#pragma unroll
    for (int n = 0; n < 8; ++n) {
      Oacc[n][0] *= corr[0]; Oacc[n][1] *= corr[1];
      Oacc[n][2] *= corr[2]; Oacc[n][3] *= corr[3];
    }
    asm volatile("s_waitcnt lgkmcnt(0)" ::: "memory");
    __builtin_amdgcn_sched_barrier(0);

    // ---- PV: O[q][dk] += P . V  (A = P from lP, B = V^T rows from lV)
#pragma unroll
    for (int kk = 0; kk < 2; ++kk) {
      const bf16x8 pa = *(const bf16x8*)(pw + lo * 128 + ((kk * 64 + hi * 16) ^ ((lo & 7) << 4)));
#pragma unroll
      for (int n = 0; n < 8; ++n) {
        const int row = n * 16 + lo;
        const bf16x8 vb = *(const bf16x8*)(lVc + row * 128 + ((kk * 64 + hi * 16) ^ ((row & 7) << 4)));
        Oacc[n] = __builtin_amdgcn_mfma_f32_16x16x32_bf16(pa, vb, Oacc[n], 0, 0, 0);
      }
    }
    __syncthreads();   // all waves done reading lK/lV before next stage
  }

  // ---- epilogue: normalize, write O^T into CTXT
  float inv[4];
#pragma unroll
  for (int r = 0; r < 4; ++r) inv[r] = 1.0f / l_r[r];
#pragma unroll
  for (int n = 0; n < 8; ++n) {
    u16x4 o;
#pragma unroll
    for (int r = 0; r < 4; ++r) {
      const bf16_t b = (bf16_t)(Oacc[n][r] * inv[r]);
      o[r] = *(const unsigned short*)&b;
    }
    *(u16x4*)(CTXT + (int64_t)(head * 128 + n * 16 + lo) * 2048 + q0 + hi * 4) = o;
  }
}

// out[c][r] = bf16(in[r][c]); grid (cols/32, rows/32), block 256 flat.
template<typename TIN>
__device__ __forceinline__
void transpose_body(const TIN* __restrict__ in, int64_t ldi,
                    bf16_t* __restrict__ out, int64_t ldo)
{
  __shared__ float tile[32][33];
  const int bx = blockIdx.x * 32;
  const int by = blockIdx.y * 32;
  const int tx = threadIdx.x & 31;
  const int ty = threadIdx.x >> 5;
#pragma unroll
  for (int i = 0; i < 32; i += 8)
    tile[ty + i][tx] = (float)in[(int64_t)(by + ty + i) * ldi + bx + tx];
  __syncthreads();
#pragma unroll
  for (int i = 0; i < 32; i += 8)
    out[(int64_t)(bx + ty + i) * ldo + by + tx] = (bf16_t)tile[tx][ty + i];
}

template<typename TIN>
__global__ __launch_bounds__(256)
void transpose_to_bf16(const TIN* __restrict__ in, int64_t ldi,
                       bf16_t* __restrict__ out, int64_t ldo)
{
  transpose_body<TIN>(in, ldi, out, ldo);
}

struct Ptr10 { const float* p[10]; };

__global__ __launch_bounds__(256)
void weight_prep(Ptr10 ws, bf16_t* __restrict__ out, int64_t stride)
{
  transpose_body<float>(ws.p[blockIdx.z], 2048, out + (int64_t)blockIdx.z * stride, 2048);
}

__global__ __launch_bounds__(256)
void f32_to_bf16_k(const float* __restrict__ in, bf16_t* __restrict__ out)
{
  const int64_t i = ((int64_t)blockIdx.x * 256 + threadIdx.x) * 8;
  const float4 a = *(const float4*)(in + i);
  const float4 b = *(const float4*)(in + i + 4);
  bf16x8 o;
  o[0] = (bf16_t)a.x; o[1] = (bf16_t)a.y; o[2] = (bf16_t)a.z; o[3] = (bf16_t)a.w;
  o[4] = (bf16_t)b.x; o[5] = (bf16_t)b.y; o[6] = (bf16_t)b.z; o[7] = (bf16_t)b.w;
  *(bf16x8*)(out + i) = o;
}

// LN(y)*g + b -> xout (fp32) and xb (bf16). One block per row.
__global__ __launch_bounds__(256)
void add_ln(const float* __restrict__ y,
            const float* __restrict__ g, const float* __restrict__ b,
            float* __restrict__ xout, bf16_t* __restrict__ xb)
{
  const int64_t row = blockIdx.x;
  const int t = threadIdx.x;
  const int64_t base = row * 2048 + t * 8;
  const float4 y0 = *(const float4*)(y + base);
  const float4 y1 = *(const float4*)(y + base + 4);
  float x[8] = {y0.x, y0.y, y0.z, y0.w, y1.x, y1.y, y1.z, y1.w};
  float s = 0.f, q = 0.f;
#pragma unroll
  for (int j = 0; j < 8; ++j) { s += x[j]; q += x[j] * x[j]; }
#pragma unroll
  for (int off = 32; off; off >>= 1) { s += __shfl_xor(s, off); q += __shfl_xor(q, off); }
  __shared__ float rs[4], rq[4];
  const int l = t & 63, w = t >> 6;
  if (l == 0) { rs[w] = s; rq[w] = q; }
  __syncthreads();
  s = rs[0] + rs[1] + rs[2] + rs[3];
  q = rq[0] + rq[1] + rq[2] + rq[3];
  const float mean = s * (1.f / 2048.f);
  const float var  = q * (1.f / 2048.f) - mean * mean;
  const float inv  = rsqrtf(var + 1e-5f);
  const float4 g0 = *(const float4*)(g + t * 8);
  const float4 g1 = *(const float4*)(g + t * 8 + 4);
  const float4 b0 = *(const float4*)(b + t * 8);
  const float4 b1 = *(const float4*)(b + t * 8 + 4);
  float o[8];
  o[0] = (x[0] - mean) * inv * g0.x + b0.x; o[1] = (x[1] - mean) * inv * g0.y + b0.y;
  o[2] = (x[2] - mean) * inv * g0.z + b0.z; o[3] = (x[3] - mean) * inv * g0.w + b0.w;
  o[4] = (x[4] - mean) * inv * g1.x + b1.x; o[5] = (x[5] - mean) * inv * g1.y + b1.y;
  o[6] = (x[6] - mean) * inv * g1.z + b1.z; o[7] = (x[7] - mean) * inv * g1.w + b1.w;
  *(float4*)(xout + base)     = make_float4(o[0], o[1], o[2], o[3]);
  *(float4*)(xout + base + 4) = make_float4(o[4], o[5], o[6], o[7]);
  bf16x8 ob;
#pragma unroll
  for (int j = 0; j < 8; ++j) ob[j] = (bf16_t)o[j];
  *(bf16x8*)(xb + base) = ob;
}

extern "C" void kernel_launch(void* const* d_in, const int* in_sizes, int n_in,
                              void* d_out, int out_size, void* d_ws, size_t ws_size,
                              hipStream_t stream)
{
  constexpr int S = 2048, D = 2048;
  constexpr int64_t DD = (int64_t)D * D;

  const float* X    = (const float*)d_in[0];
  const float* wq1  = (const float*)d_in[1];
  const float* wk1  = (const float*)d_in[2];
  const float* wv1  = (const float*)d_in[3];
  const float* wfc1 = (const float*)d_in[4];
  const float* bfc1 = (const float*)d_in[5];
  const float* g1   = (const float*)d_in[6];
  const float* b1   = (const float*)d_in[7];
  const float* wl1  = (const float*)d_in[8];
  const float* bl1  = (const float*)d_in[9];
  const float* g2   = (const float*)d_in[10];
  const float* b2   = (const float*)d_in[11];
  const float* wq2  = (const float*)d_in[12];
  const float* wk2  = (const float*)d_in[13];
  const float* wv2  = (const float*)d_in[14];
  const float* wfc2 = (const float*)d_in[15];
  const float* bfc2 = (const float*)d_in[16];
  const float* g3   = (const float*)d_in[17];
  const float* b3   = (const float*)d_in[18];
  const float* wl2  = (const float*)d_in[19];
  const float* bl2  = (const float*)d_in[20];
  const float* g4   = (const float*)d_in[21];
  const float* b4   = (const float*)d_in[22];

  // workspace layout
  char* p = (char*)d_ws;
  bf16_t* WT  = (bf16_t*)p; p += 10 * DD * 2;            // transposed bf16 weights
  bf16_t* Xb  = (bf16_t*)p; p += DD * 2;                 // current X bf16
  bf16_t* QKV = (bf16_t*)p; p += (int64_t)S * 3 * D * 2; // S x 6144
  bf16_t* VT  = (bf16_t*)p; p += DD * 2;                 // V^T feature-major
  bf16_t* CTXT= (bf16_t*)p; p += DD * 2;                 // ctx^T (= scrambled reshape)
  float*  OUTF= (float*)p;  p += DD * 4;                 // fp32 GEMM out (+res)
  float*  XF  = (float*)p;                               // current X fp32

  const dim3 TB(256);

  auto gemm = [&](const bf16_t* A, int64_t lda,
                  const bf16_t* BT, int64_t ldb,
                  void* C, int64_t ldc,
                  const float* bias, const float* res, float scale,
                  int M, int N, int K, bool obf) {
    dim3 gg(N / 128, M / 128, 1);
    if (obf) gemm_bt<true, false, false><<<gg, TB, 0, stream>>>(A, lda, 0, BT, ldb, 0, C, ldc, 0, nullptr, nullptr, scale, K);
    else     gemm_bt<false, true, true ><<<gg, TB, 0, stream>>>(A, lda, 0, BT, ldb, 0, C, ldc, 0, bias, res, scale, K);
  };

  Ptr10 wsrc = {{wq1, wk1, wv1, wfc1, wl1, wq2, wk2, wv2, wfc2, wl2}};
  weight_prep<<<dim3(64, 64, 10), TB, 0, stream>>>(wsrc, WT, DD);
  f32_to_bf16_k<<<dim3(DD / 2048), TB, 0, stream>>>(X, Xb);

  auto layer = [&](const float* resX, int sq, int sfc, int sfl,
                   const float* bfc, const float* ga, const float* ba,
                   const float* bl, const float* gb, const float* bb,
                   float* ln2_out) {
    // fused QKV projection (weight slots sq..sq+2 contiguous)
    gemm(Xb, D, WT + (int64_t)sq * DD, D, QKV, 3 * D, nullptr, nullptr, 1.f, S, 3 * D, D, true);
    // V^T (feature-major; per-head V_h^T stacked)
    transpose_to_bf16<bf16_t><<<dim3(64, 64), TB, 0, stream>>>(QKV + 2 * D, 3 * D, VT, S);
    // fused attention -> CTXT
    flash_attn<<<dim3(32, 16), TB, 0, stream>>>(QKV, VT, CTXT);
    // fc on scrambled-reshape matrix (= CTXT), residual fused
    gemm(CTXT, S, WT + (int64_t)sfc * DD, D, OUTF, D, bfc, resX, 1.f, D, D, S, false);
    add_ln<<<dim3(S), TB, 0, stream>>>(OUTF, ga, ba, XF, Xb);
    // FFN linear, residual fused
    gemm(Xb, D, WT + (int64_t)sfl * DD, D, OUTF, D, bl, XF, 1.f, S, D, D, false);
    add_ln<<<dim3(S), TB, 0, stream>>>(OUTF, gb, bb, ln2_out, Xb);
  };

  layer(X,  0, 3, 4, bfc1, g1, b1, bl1, g2, b2, XF);
  layer(XF, 5, 8, 9, bfc2, g3, b3, bl2, g4, b4, (float*)d_out);
}

// Round 8
// 805.889 us; speedup vs baseline: 1.4605x; 1.0540x over previous
//
#include <hip/hip_runtime.h>
#include <stdint.h>

typedef __bf16 bf16_t;
typedef __bf16 bf16x8 __attribute__((ext_vector_type(8)));
typedef float  f32x4  __attribute__((ext_vector_type(4)));

__device__ __forceinline__ void gl_lds16(const void* g, void* lds) {
  __builtin_amdgcn_global_load_lds(
      (const __attribute__((address_space(1))) uint32_t*)g,
      (__attribute__((address_space(3))) uint32_t*)lds, 16, 0, 0);
}

// C[m][n] = (sum_k A[m][k] * BT[n][k]) * scale + bias[n] (+ res[m][n])
// A: M x K bf16 (lda), BT: N x K bf16 (ldb). 128x128 tile, BK=32,
// 256 thr = 4 waves (2x2), each wave 64x64 = 4x4 of mfma_f32_16x16x32_bf16.
// blockIdx.z strides: sA/sB are K-offsets (elements), sC a C-buffer offset —
// used both for batching and for split-K partials.
template<bool OUT_BF16, bool HAS_BIAS, bool HAS_RES>
__global__ __launch_bounds__(256)
void gemm_bt(const bf16_t* __restrict__ A, int64_t lda, int64_t sA,
             const bf16_t* __restrict__ BT, int64_t ldb, int64_t sB,
             void* __restrict__ Cv, int64_t ldc, int64_t sC,
             const float* __restrict__ bias, const float* __restrict__ res,
             float scale, int K)
{
  __shared__ __align__(16) bf16_t lA[128 * 32];
  __shared__ __align__(16) bf16_t lB[128 * 32];
  const int t = threadIdx.x;
  const int z = blockIdx.z;

  // T1: XCD swizzle (bijective only when nwg % 8 == 0 — true for all launches here)
  const int gx  = gridDim.x;
  const int nwg = gx * gridDim.y;
  int flat = blockIdx.y * gx + blockIdx.x;
  if ((nwg & 7) == 0) flat = (flat & 7) * (nwg >> 3) + (flat >> 3);
  const int tn = flat % gx;
  const int tm = flat / gx;

  const bf16_t* Ab = A + (int64_t)z * sA;
  const bf16_t* Bb = BT + (int64_t)z * sB;
  const int64_t bm = (int64_t)tm * 128;
  const int64_t bn = (int64_t)tn * 128;
  const int l   = t & 63;
  const int wid = t >> 6;
  const int wm  = (wid >> 1) * 64;
  const int wn  = (wid & 1) * 64;
  const int lr  = l & 15;
  const int kg  = l >> 4;
  const int srow = t >> 2;
  const int scol = (t & 3) * 8;
  char* lAc = (char*)lA;
  char* lBc = (char*)lB;
  const int wbase = (t & 192) * 16;

  f32x4 acc[4][4] = {};

  for (int k0 = 0; k0 < K; k0 += 32) {
    const bf16_t* ga = Ab + (bm + srow) * lda + k0 + scol;
    const bf16_t* gb = Bb + (bn + srow) * ldb + k0 + scol;
    gl_lds16(ga,            lAc + wbase);
    gl_lds16(ga + 64 * lda, lAc + 4096 + wbase);
    gl_lds16(gb,            lBc + wbase);
    gl_lds16(gb + 64 * ldb, lBc + 4096 + wbase);
    __syncthreads();
    bf16x8 af[4], bfv[4];
#pragma unroll
    for (int m = 0; m < 4; ++m)
      af[m] = *(const bf16x8*)(lA + (wm + m * 16 + lr) * 32 + kg * 8);
#pragma unroll
    for (int n = 0; n < 4; ++n)
      bfv[n] = *(const bf16x8*)(lB + (wn + n * 16 + lr) * 32 + kg * 8);
#pragma unroll
    for (int m = 0; m < 4; ++m)
#pragma unroll
      for (int n = 0; n < 4; ++n)
        acc[m][n] = __builtin_amdgcn_mfma_f32_16x16x32_bf16(af[m], bfv[n], acc[m][n], 0, 0, 0);
    __syncthreads();
  }

  bf16_t* C16 = (bf16_t*)Cv + (int64_t)z * sC;
  float*  C32 = (float*)Cv + (int64_t)z * sC;
#pragma unroll
  for (int m = 0; m < 4; ++m) {
#pragma unroll
    for (int n = 0; n < 4; ++n) {
      const int64_t col = bn + wn + n * 16 + lr;
      const float bv = HAS_BIAS ? bias[col] : 0.0f;
#pragma unroll
      for (int r = 0; r < 4; ++r) {
        const int64_t row = bm + wm + m * 16 + kg * 4 + r;
        float v = acc[m][n][r] * scale + bv;
        if constexpr (HAS_RES) v += res[row * ldc + col];
        if constexpr (OUT_BF16) C16[row * ldc + col] = (bf16_t)v;
        else                    C32[row * ldc + col] = v;
      }
    }
  }
}

// Fused flash attention, LDS-staged K/V, split-KV over blockIdx.z (2 halves).
// Grid (32 qtiles, 16 heads, 2), 256 thr = 4 waves; each wave owns 16 q-rows.
// Each half processes 16 KV tiles (KVBLK=64) and writes a locally-normalized
// fp32 partial O (d-major) + per-row (m, l); merge_attn combines the halves.
__global__ __launch_bounds__(256)
void flash_attn(const bf16_t* __restrict__ QKV,   // S x 6144
                const bf16_t* __restrict__ VT,    // 2048 x 2048 feature-major
                float* __restrict__ Opart,        // [2][2048][2048] d-major
                float* __restrict__ Mb,           // [2][16][2048]
                float* __restrict__ Lb)           // [2][16][2048]
{
  __shared__ __align__(16) bf16_t lK[64 * 128];   // [kv][dk]   row 256 B, swizzled
  __shared__ __align__(16) bf16_t lV[128 * 64];   // [dk][kv]   row 128 B, swizzled
  __shared__ __align__(16) bf16_t lP[4][16 * 64]; // per-wave P, row 128 B, swizzled
  const int t = threadIdx.x;
  const int w = t >> 6, l = t & 63, lo = l & 15, hi = l >> 4;
  const int head = blockIdx.y;
  const int qt = blockIdx.x;
  const int z = blockIdx.z;
  const int q0 = qt * 64 + w * 16;
  const int wbase = (t & 192) * 16;  // wave-uniform LDS byte base (w*1024)

  // Q A-frags: row = lo, k = 32*kk + hi*8 + j
  const bf16_t* qp = QKV + (int64_t)(q0 + lo) * 6144 + head * 128 + hi * 8;
  bf16x8 qf[4];
#pragma unroll
  for (int kk = 0; kk < 4; ++kk) qf[kk] = *(const bf16x8*)(qp + 32 * kk);

  const bf16_t* kbase = QKV + 2048 + head * 128;           // [kv][*] ld 6144
  const bf16_t* vbase = VT + (int64_t)(head * 128) * 2048; // [dk][kv] ld 2048

  float m_r[4], l_r[4];
  f32x4 Oacc[8] = {};
#pragma unroll
  for (int r = 0; r < 4; ++r) { m_r[r] = -3.0e38f; l_r[r] = 0.f; }

  const float c1 = 0.08838834764831845f * 1.4426950408889634f; // 1/sqrt(dk)*log2e

  char* lKc = (char*)lK;
  char* lVc = (char*)lV;
  char* pw  = (char*)lP[w];

  for (int tile = 0; tile < 16; ++tile) {
    const int kv0 = z * 1024 + tile * 64;
    // ---- stage K tile: 16 KB, 4 rounds; dest linear, source inverse-swizzled
#pragma unroll
    for (int c = 0; c < 4; ++c) {
      const int row = c * 16 + (t >> 4);                 // kv-local 0..63
      const int srcb = ((t & 15) * 16) ^ ((row & 7) << 4);
      gl_lds16(kbase + (int64_t)(kv0 + row) * 6144 + (srcb >> 1), lKc + c * 4096 + wbase);
    }
    // ---- stage V^T tile: 16 KB, 4 rounds
#pragma unroll
    for (int c = 0; c < 4; ++c) {
      const int row = c * 32 + (t >> 3);                 // dk-local 0..127
      const int srcb = ((t & 7) * 16) ^ ((row & 7) << 4);
      gl_lds16(vbase + (int64_t)row * 2048 + kv0 + (srcb >> 1), lVc + c * 4096 + wbase);
    }
    __syncthreads();

    // ---- scores: S[q][kv] = Q . K^T  (B-frags from swizzled lK)
    f32x4 Sacc[4] = {};
#pragma unroll
    for (int kk = 0; kk < 4; ++kk) {
      bf16x8 kb[4];
#pragma unroll
      for (int n = 0; n < 4; ++n) {
        const int row = n * 16 + lo;
        kb[n] = *(const bf16x8*)(lKc + row * 256 + ((kk * 64 + hi * 16) ^ ((row & 7) << 4)));
      }
#pragma unroll
      for (int n = 0; n < 4; ++n)
        Sacc[n] = __builtin_amdgcn_mfma_f32_16x16x32_bf16(qf[kk], kb[n], Sacc[n], 0, 0, 0);
    }

    // ---- online softmax; q-row = hi*4+r, kv = n*16+lo; reduce across lo lanes
    float corr[4];
#pragma unroll
    for (int r = 0; r < 4; ++r) {
      float mx = Sacc[0][r];
#pragma unroll
      for (int n = 1; n < 4; ++n) mx = fmaxf(mx, Sacc[n][r]);
#pragma unroll
      for (int off = 1; off < 16; off <<= 1) mx = fmaxf(mx, __shfl_xor(mx, off));
      const float mt = mx * c1;
      const float mnew = fmaxf(m_r[r], mt);
      corr[r] = exp2f(m_r[r] - mnew);
      m_r[r] = mnew;
    }
    float psum[4] = {0.f, 0.f, 0.f, 0.f};
#pragma unroll
    for (int n = 0; n < 4; ++n) {
#pragma unroll
      for (int r = 0; r < 4; ++r) {
        const float p = exp2f(Sacc[n][r] * c1 - m_r[r]);
        psum[r] += p;
        const int row = hi * 4 + r;
        const int byte = row * 128 + (((n * 16 + lo) * 2) ^ ((row & 7) << 4));
        *(bf16_t*)(pw + byte) = (bf16_t)p;
      }
    }
#pragma unroll
    for (int r = 0; r < 4; ++r) {
#pragma unroll
      for (int off = 1; off < 16; off <<= 1) psum[r] += __shfl_xor(psum[r], off);
      l_r[r] = l_r[r] * corr[r] + psum[r];
    }
#pragma unroll
    for (int n = 0; n < 8; ++n) {
      Oacc[n][0] *= corr[0]; Oacc[n][1] *= corr[1];
      Oacc[n][2] *= corr[2]; Oacc[n][3] *= corr[3];
    }
    asm volatile("s_waitcnt lgkmcnt(0)" ::: "memory");
    __builtin_amdgcn_sched_barrier(0);

    // ---- PV: O[q][dk] += P . V  (A = P from lP, B = V^T rows from lV)
#pragma unroll
    for (int kk = 0; kk < 2; ++kk) {
      const bf16x8 pa = *(const bf16x8*)(pw + lo * 128 + ((kk * 64 + hi * 16) ^ ((lo & 7) << 4)));
#pragma unroll
      for (int n = 0; n < 8; ++n) {
        const int row = n * 16 + lo;
        const bf16x8 vb = *(const bf16x8*)(lVc + row * 128 + ((kk * 64 + hi * 16) ^ ((row & 7) << 4)));
        Oacc[n] = __builtin_amdgcn_mfma_f32_16x16x32_bf16(pa, vb, Oacc[n], 0, 0, 0);
      }
    }
    __syncthreads();   // all waves done reading lK/lV before next stage
  }

  // ---- epilogue: locally-normalized fp32 partial O (d-major) + (m, l)
  float inv[4];
#pragma unroll
  for (int r = 0; r < 4; ++r) inv[r] = 1.0f / l_r[r];
  float* op = Opart + (int64_t)z * 2048 * 2048 + (int64_t)(head * 128) * 2048;
#pragma unroll
  for (int n = 0; n < 8; ++n) {
    f32x4 o = {Oacc[n][0] * inv[0], Oacc[n][1] * inv[1],
               Oacc[n][2] * inv[2], Oacc[n][3] * inv[3]};
    *(f32x4*)(op + (int64_t)(n * 16 + lo) * 2048 + q0 + hi * 4) = o;
  }
  if (lo == 0) {
    const int mlb = (z * 16 + head) * 2048 + q0 + hi * 4;
#pragma unroll
    for (int r = 0; r < 4; ++r) { Mb[mlb + r] = m_r[r]; Lb[mlb + r] = l_r[r]; }
  }
}

// Merge the two split-KV halves: one block per d-row (2048), 256 thr x 8 q.
__global__ __launch_bounds__(256)
void merge_attn(const float* __restrict__ Opart, const float* __restrict__ Mb,
                const float* __restrict__ Lb, bf16_t* __restrict__ CTXT)
{
  const int row = blockIdx.x;
  const int head = row >> 7;
  const int q = threadIdx.x * 8;
  const int64_t DD = 2048LL * 2048;
  const float* o0 = Opart + (int64_t)row * 2048;
  const float* o1 = o0 + DD;
  const float* m0p = Mb + head * 2048;
  const float* m1p = m0p + 16 * 2048;
  const float* l0p = Lb + head * 2048;
  const float* l1p = l0p + 16 * 2048;
  bf16x8 out;
#pragma unroll
  for (int h = 0; h < 2; ++h) {
    const int qq = q + h * 4;
    const float4 a  = *(const float4*)(o0 + qq);
    const float4 c  = *(const float4*)(o1 + qq);
    const float4 m0 = *(const float4*)(m0p + qq);
    const float4 m1 = *(const float4*)(m1p + qq);
    const float4 l0 = *(const float4*)(l0p + qq);
    const float4 l1 = *(const float4*)(l1p + qq);
    const float oa[4] = {a.x, a.y, a.z, a.w}, oc[4] = {c.x, c.y, c.z, c.w};
    const float ma[4] = {m0.x, m0.y, m0.z, m0.w}, mc[4] = {m1.x, m1.y, m1.z, m1.w};
    const float la[4] = {l0.x, l0.y, l0.z, l0.w}, lc[4] = {l1.x, l1.y, l1.z, l1.w};
#pragma unroll
    for (int j = 0; j < 4; ++j) {
      const float m  = fmaxf(ma[j], mc[j]);
      const float w0 = la[j] * exp2f(ma[j] - m);
      const float w1 = lc[j] * exp2f(mc[j] - m);
      out[h * 4 + j] = (bf16_t)((w0 * oa[j] + w1 * oc[j]) / (w0 + w1));
    }
  }
  *(bf16x8*)(CTXT + (int64_t)row * 2048 + q) = out;
}

// out[c][r] = bf16(in[r][c]); grid (cols/32, rows/32), block 256 flat.
template<typename TIN>
__device__ __forceinline__
void transpose_body(const TIN* __restrict__ in, int64_t ldi,
                    bf16_t* __restrict__ out, int64_t ldo)
{
  __shared__ float tile[32][33];
  const int bx = blockIdx.x * 32;
  const int by = blockIdx.y * 32;
  const int tx = threadIdx.x & 31;
  const int ty = threadIdx.x >> 5;
#pragma unroll
  for (int i = 0; i < 32; i += 8)
    tile[ty + i][tx] = (float)in[(int64_t)(by + ty + i) * ldi + bx + tx];
  __syncthreads();
#pragma unroll
  for (int i = 0; i < 32; i += 8)
    out[(int64_t)(bx + ty + i) * ldo + by + tx] = (bf16_t)tile[tx][ty + i];
}

template<typename TIN>
__global__ __launch_bounds__(256)
void transpose_to_bf16(const TIN* __restrict__ in, int64_t ldi,
                       bf16_t* __restrict__ out, int64_t ldo)
{
  transpose_body<TIN>(in, ldi, out, ldo);
}

struct Ptr10 { const float* p[10]; };

__global__ __launch_bounds__(256)
void weight_prep(Ptr10 ws, bf16_t* __restrict__ out, int64_t stride)
{
  transpose_body<float>(ws.p[blockIdx.z], 2048, out + (int64_t)blockIdx.z * stride, 2048);
}

__global__ __launch_bounds__(256)
void f32_to_bf16_k(const float* __restrict__ in, bf16_t* __restrict__ out)
{
  const int64_t i = ((int64_t)blockIdx.x * 256 + threadIdx.x) * 8;
  const float4 a = *(const float4*)(in + i);
  const float4 b = *(const float4*)(in + i + 4);
  bf16x8 o;
  o[0] = (bf16_t)a.x; o[1] = (bf16_t)a.y; o[2] = (bf16_t)a.z; o[3] = (bf16_t)a.w;
  o[4] = (bf16_t)b.x; o[5] = (bf16_t)b.y; o[6] = (bf16_t)b.z; o[7] = (bf16_t)b.w;
  *(bf16x8*)(out + i) = o;
}

// x = y0 + y1 + res + bias; LN(x)*g + b -> xout (fp32) and xb (bf16).
__global__ __launch_bounds__(256)
void add_ln2(const float* __restrict__ y0, const float* __restrict__ y1,
             const float* __restrict__ res, const float* __restrict__ bias,
             const float* __restrict__ g, const float* __restrict__ b,
             float* __restrict__ xout, bf16_t* __restrict__ xb)
{
  const int64_t row = blockIdx.x;
  const int t = threadIdx.x;
  const int64_t base = row * 2048 + t * 8;
  const float4 a0 = *(const float4*)(y0 + base);
  const float4 a1 = *(const float4*)(y0 + base + 4);
  const float4 c0 = *(const float4*)(y1 + base);
  const float4 c1 = *(const float4*)(y1 + base + 4);
  const float4 r0 = *(const float4*)(res + base);
  const float4 r1 = *(const float4*)(res + base + 4);
  const float4 e0 = *(const float4*)(bias + t * 8);
  const float4 e1 = *(const float4*)(bias + t * 8 + 4);
  float x[8] = {a0.x + c0.x + r0.x + e0.x, a0.y + c0.y + r0.y + e0.y,
                a0.z + c0.z + r0.z + e0.z, a0.w + c0.w + r0.w + e0.w,
                a1.x + c1.x + r1.x + e1.x, a1.y + c1.y + r1.y + e1.y,
                a1.z + c1.z + r1.z + e1.z, a1.w + c1.w + r1.w + e1.w};
  float s = 0.f, q = 0.f;
#pragma unroll
  for (int j = 0; j < 8; ++j) { s += x[j]; q += x[j] * x[j]; }
#pragma unroll
  for (int off = 32; off; off >>= 1) { s += __shfl_xor(s, off); q += __shfl_xor(q, off); }
  __shared__ float rs[4], rq[4];
  const int l = t & 63, w = t >> 6;
  if (l == 0) { rs[w] = s; rq[w] = q; }
  __syncthreads();
  s = rs[0] + rs[1] + rs[2] + rs[3];
  q = rq[0] + rq[1] + rq[2] + rq[3];
  const float mean = s * (1.f / 2048.f);
  const float var  = q * (1.f / 2048.f) - mean * mean;
  const float inv  = rsqrtf(var + 1e-5f);
  const float4 g0 = *(const float4*)(g + t * 8);
  const float4 g1 = *(const float4*)(g + t * 8 + 4);
  const float4 b0 = *(const float4*)(b + t * 8);
  const float4 b1 = *(const float4*)(b + t * 8 + 4);
  float o[8];
  o[0] = (x[0] - mean) * inv * g0.x + b0.x; o[1] = (x[1] - mean) * inv * g0.y + b0.y;
  o[2] = (x[2] - mean) * inv * g0.z + b0.z; o[3] = (x[3] - mean) * inv * g0.w + b0.w;
  o[4] = (x[4] - mean) * inv * g1.x + b1.x; o[5] = (x[5] - mean) * inv * g1.y + b1.y;
  o[6] = (x[6] - mean) * inv * g1.z + b1.z; o[7] = (x[7] - mean) * inv * g1.w + b1.w;
  *(float4*)(xout + base)     = make_float4(o[0], o[1], o[2], o[3]);
  *(float4*)(xout + base + 4) = make_float4(o[4], o[5], o[6], o[7]);
  bf16x8 ob;
#pragma unroll
  for (int j = 0; j < 8; ++j) ob[j] = (bf16_t)o[j];
  *(bf16x8*)(xb + base) = ob;
}

extern "C" void kernel_launch(void* const* d_in, const int* in_sizes, int n_in,
                              void* d_out, int out_size, void* d_ws, size_t ws_size,
                              hipStream_t stream)
{
  constexpr int S = 2048, D = 2048;
  constexpr int64_t DD = (int64_t)D * D;

  const float* X    = (const float*)d_in[0];
  const float* wq1  = (const float*)d_in[1];
  const float* wk1  = (const float*)d_in[2];
  const float* wv1  = (const float*)d_in[3];
  const float* wfc1 = (const float*)d_in[4];
  const float* bfc1 = (const float*)d_in[5];
  const float* g1   = (const float*)d_in[6];
  const float* b1   = (const float*)d_in[7];
  const float* wl1  = (const float*)d_in[8];
  const float* bl1  = (const float*)d_in[9];
  const float* g2   = (const float*)d_in[10];
  const float* b2   = (const float*)d_in[11];
  const float* wq2  = (const float*)d_in[12];
  const float* wk2  = (const float*)d_in[13];
  const float* wv2  = (const float*)d_in[14];
  const float* wfc2 = (const float*)d_in[15];
  const float* bfc2 = (const float*)d_in[16];
  const float* g3   = (const float*)d_in[17];
  const float* b3   = (const float*)d_in[18];
  const float* wl2  = (const float*)d_in[19];
  const float* bl2  = (const float*)d_in[20];
  const float* g4   = (const float*)d_in[21];
  const float* b4   = (const float*)d_in[22];

  // workspace layout (~209 MB)
  char* p = (char*)d_ws;
  bf16_t* WT   = (bf16_t*)p; p += 10 * DD * 2;            // transposed bf16 weights
  bf16_t* Xb   = (bf16_t*)p; p += DD * 2;                 // current X bf16
  bf16_t* QKV  = (bf16_t*)p; p += (int64_t)S * 3 * D * 2; // S x 6144
  bf16_t* VT   = (bf16_t*)p; p += DD * 2;                 // V^T feature-major
  bf16_t* CTXT = (bf16_t*)p; p += DD * 2;                 // ctx^T (= scrambled reshape)
  float*  OUTF = (float*)p;  p += 2 * DD * 4;             // split-K partials (2 bufs)
  float*  XF   = (float*)p;  p += DD * 4;                 // current X fp32
  float*  OP   = (float*)p;  p += 2 * DD * 4;             // attn partial O (2 halves)
  float*  Mb   = (float*)p;  p += 2 * 16 * 2048 * 4;      // attn partial m
  float*  Lb   = (float*)p;                               // attn partial l

  const dim3 TB(256);

  auto gemm_full = [&](const bf16_t* A, int64_t lda,
                       const bf16_t* BT, int64_t ldb,
                       void* C, int64_t ldc, int M, int N, int K) {
    dim3 gg(N / 128, M / 128, 1);
    gemm_bt<true, false, false><<<gg, TB, 0, stream>>>(A, lda, 0, BT, ldb, 0, C, ldc, 0,
                                                       nullptr, nullptr, 1.f, K);
  };
  auto gemm_splitk = [&](const bf16_t* A, int64_t lda,
                         const bf16_t* BT, int64_t ldb, float* C) {
    dim3 gg(16, 16, 2);   // 2048x2048, K=2048 split in 2x1024
    gemm_bt<false, false, false><<<gg, TB, 0, stream>>>(A, lda, 1024, BT, ldb, 1024,
                                                        C, D, DD, nullptr, nullptr, 1.f, 1024);
  };

  Ptr10 wsrc = {{wq1, wk1, wv1, wfc1, wl1, wq2, wk2, wv2, wfc2, wl2}};
  weight_prep<<<dim3(64, 64, 10), TB, 0, stream>>>(wsrc, WT, DD);
  f32_to_bf16_k<<<dim3(DD / 2048), TB, 0, stream>>>(X, Xb);

  auto layer = [&](const float* resX, int sq, int sfc, int sfl,
                   const float* bfc, const float* ga, const float* ba,
                   const float* bl, const float* gb, const float* bb,
                   float* ln2_out) {
    // fused QKV projection (weight slots sq..sq+2 contiguous)
    gemm_full(Xb, D, WT + (int64_t)sq * DD, D, QKV, 3 * D, S, 3 * D, D);
    // V^T (feature-major; per-head V_h^T stacked)
    transpose_to_bf16<bf16_t><<<dim3(64, 64), TB, 0, stream>>>(QKV + 2 * D, 3 * D, VT, S);
    // fused attention (split-KV) -> partials -> merge -> CTXT
    flash_attn<<<dim3(32, 16, 2), TB, 0, stream>>>(QKV, VT, OP, Mb, Lb);
    merge_attn<<<dim3(2048), TB, 0, stream>>>(OP, Mb, Lb, CTXT);
    // fc on scrambled-reshape matrix (= CTXT), split-K partials
    gemm_splitk(CTXT, S, WT + (int64_t)sfc * DD, D, OUTF);
    add_ln2<<<dim3(S), TB, 0, stream>>>(OUTF, OUTF + DD, resX, bfc, ga, ba, XF, Xb);
    // FFN linear, split-K partials
    gemm_splitk(Xb, D, WT + (int64_t)sfl * DD, D, OUTF);
    add_ln2<<<dim3(S), TB, 0, stream>>>(OUTF, OUTF + DD, XF, bl, gb, bb, ln2_out, Xb);
  };

  layer(X,  0, 3, 4, bfc1, g1, b1, bl1, g2, b2, XF);
  layer(XF, 5, 8, 9, bfc2, g3, b3, bl2, g4, b4, (float*)d_out);
}